// Round 12
// baseline (2536.656 us; speedup 1.0000x reference)
//
#include <hip/hip_runtime.h>
#include <stdint.h>

#define N_PTS 100000
#define NPAD  100032   // 64-divisible

typedef unsigned short u16;
typedef unsigned int   u32;
using bf16x8 = __attribute__((ext_vector_type(8))) short;
using f32x4  = __attribute__((ext_vector_type(4))) float;

__device__ __forceinline__ u16 f2bf(float f) {
    u32 u = __float_as_uint(f);
    u += 0x7FFFu + ((u >> 16) & 1u);   // RNE
    return (u16)(u >> 16);
}
__device__ __forceinline__ float bf2f(u16 h) {
    return __uint_as_float(((u32)h) << 16);
}

// ---------- padded transpose to bf16: dst[l][co][stride] = src[l][ci][co] (ci<R else 0)
__global__ __launch_bounds__(256) void k_transpose_pad(
    const float* __restrict__ src, u16* __restrict__ dst,
    int Lc, int R, int Cc, int stride) {
    int t = blockIdx.x * 256 + threadIdx.x;
    int total = Lc * Cc * stride;
    if (t >= total) return;
    int l = t / (Cc * stride);
    int rem = t - l * (Cc * stride);
    int co = rem / stride;
    int ci = rem - co * stride;
    dst[t] = (ci < R) ? f2bf(src[((size_t)l * R + ci) * Cc + co]) : (u16)0;
}

__global__ __launch_bounds__(256) void k_cast_bf16(
    const float* __restrict__ src, u16* __restrict__ dst, int total) {
    int t = blockIdx.x * 256 + threadIdx.x;
    if (t < total) dst[t] = f2bf(src[t]);
}

// vectorized fp32 -> bf16 cast, 8 elements/thread
__global__ __launch_bounds__(256) void k_castx8(
    const float* __restrict__ src, u16* __restrict__ dst, int total8) {
    int t = blockIdx.x * 256 + threadIdx.x;
    if (t >= total8) return;
    float4 a = *(const float4*)(src + (size_t)t * 8);
    float4 b = *(const float4*)(src + (size_t)t * 8 + 4);
    uint4 o;
    o.x = (u32)f2bf(a.x) | ((u32)f2bf(a.y) << 16);
    o.y = (u32)f2bf(a.z) | ((u32)f2bf(a.w) << 16);
    o.z = (u32)f2bf(b.x) | ((u32)f2bf(b.y) << 16);
    o.w = (u32)f2bf(b.z) | ((u32)f2bf(b.w) << 16);
    *(uint4*)(dst + (size_t)t * 8) = o;
}

// ---------- PPF features (bf16 output)
__device__ __forceinline__ float angf(float ax, float ay, float az,
                                      float bx, float by, float bz) {
    float cx = ay * bz - az * by;
    float cy = az * bx - ax * bz;
    float cz = ax * by - ay * bx;
    float cr = sqrtf(cx * cx + cy * cy + cz * cz);
    float dt = ax * bx + ay * by + az * bz;
    return atan2f(cr, dt);
}

__global__ __launch_bounds__(256) void k_ppf(
    const float* __restrict__ p, const float* __restrict__ nrm,
    const int* __restrict__ idx, const float* __restrict__ r,
    u16* __restrict__ f5b) {
    int t = blockIdx.x * 256 + threadIdx.x;
    if (t >= N_PTS * 16) return;
    int i = t >> 4;
    int j = idx[(size_t)i * 32 + (t & 15)];
    float pix = p[(size_t)i*3], piy = p[(size_t)i*3+1], piz = p[(size_t)i*3+2];
    float pjx = p[(size_t)j*3], pjy = p[(size_t)j*3+1], pjz = p[(size_t)j*3+2];
    float dx = pjx - pix, dy = pjy - piy, dz = pjz - piz;
    float dist = sqrtf(dx*dx + dy*dy + dz*dz);
    float nix = nrm[(size_t)i*3], niy = nrm[(size_t)i*3+1], niz = nrm[(size_t)i*3+2];
    float njx = nrm[(size_t)j*3], njy = nrm[(size_t)j*3+1], njz = nrm[(size_t)j*3+2];
    float a1 = angf(nix, niy, niz, dx, dy, dz);
    float a2 = angf(njx, njy, njz, dx, dy, dz);
    float a3 = angf(nix, niy, niz, njx, njy, njz);
    float rinv = 1.0f / r[0];
    u16* o = f5b + (size_t)t * 5;
    o[0] = f2bf(a1); o[1] = f2bf(a2); o[2] = f2bf(a3);
    o[3] = f2bf(dist); o[4] = f2bf(dist * rinv);
}

// Build an h A-fragment (m = neighbor rr, k = couts) from swapped-emb D-tiles.
__device__ __forceinline__ bf16x8 fixup_frag(const uint2* pk, int kt,
                                             int srcA, int srcB, bool hiT) {
    int aLx = __shfl((int)pk[2*kt].x,   srcA);
    int aHx = __shfl((int)pk[2*kt+1].x, srcA);
    int aLy = __shfl((int)pk[2*kt].y,   srcA);
    int aHy = __shfl((int)pk[2*kt+1].y, srcA);
    int bLx = __shfl((int)pk[2*kt].x,   srcB);
    int bHx = __shfl((int)pk[2*kt+1].x, srcB);
    int bLy = __shfl((int)pk[2*kt].y,   srcB);
    int bHy = __shfl((int)pk[2*kt+1].y, srcB);
    uint4 u;
    u.x = (u32)(hiT ? aHx : aLx);
    u.y = (u32)(hiT ? aHy : aLy);
    u.z = (u32)(hiT ? bHx : bLx);
    u.w = (u32)(hiT ? bHy : bLy);
    return *(bf16x8*)&u;
}

// ---------- neighbor stage v12: 32-cout eighth phases, LDS 45.5 KB -> 3 blocks/CU.
// Same access patterns as R11 (clean 128B gathers per eighth-pair, one-shot row writes).
__global__ __launch_bounds__(512, 8) void k_neighbor(
    const u16*   __restrict__ xcur,   // [*][256] bf16 gather source
    const u16*   __restrict__ f5b,    // [N][16][5] bf16
    const int*   __restrict__ idx,
    const u16*   __restrict__ w1pad,  // [256][32]
    const float* __restrict__ g1, const float* __restrict__ b1,
    const u16*   __restrict__ ew2tp,  // [256][264]
    const u16*   __restrict__ convbf, // [64][64]
    u16*         __restrict__ pooledb)// [NPAD][256] bf16
{
    __shared__ u16 Bs[32 * 264];           // 16,896 B: one 32-cout eighth
    __shared__ u16 posw[8][2][16][40];     // 20,480 B: per-wave pos (32 couts, padded 40)
    __shared__ u16 pbounce[8][2][256];     //  8,192 B: per-wave pooled rows
    __shared__ int idxs[16][16];           //  1,024 B   (total 46,592)

    const int tid = threadIdx.x, w = tid >> 6, lane = tid & 63;
    const int rr = lane & 15, q = lane >> 4;
    const int i0 = blockIdx.x * 16;

    // stage eighth 0 + idxs (overlaps emb compute)
    for (int o = tid * 16; o < 16896; o += 8192)
        *(uint4*)((char*)Bs + o) = *(const uint4*)((const char*)ew2tp + o);
    if (tid < 256)
        idxs[tid >> 4][tid & 15] = idx[(size_t)(i0 + (tid >> 4)) * 32 + (tid & 15)];

    const int srcA = rr + ((q & 1) << 5);
    const int srcB = srcA + 16;
    const bool hiT = (q >> 1) != 0;

    // ---- emb (swapped): lane rr = neighbor, in-lane couts; LN; fixup -> hfrag ----
    bf16x8 hfrag[2][8];
    #pragma unroll
    for (int rt = 0; rt < 2; ++rt) {
        const int pt = i0 + 2 * w + rt;
        bf16x8 a1;
        #pragma unroll
        for (int e = 0; e < 8; ++e) a1[e] = 0;
        if (q == 0) {
            const u16* fp = f5b + (size_t)(pt * 16 + rr) * 5;
            a1[0] = (short)fp[0]; a1[1] = (short)fp[1];
            a1[2] = (short)fp[2]; a1[3] = (short)fp[3];
            a1[4] = (short)fp[4];
        }
        f32x4 hacc[16];
        __builtin_amdgcn_s_setprio(1);
        #pragma unroll
        for (int ct = 0; ct < 16; ++ct) {
            bf16x8 aW = *(const bf16x8*)&w1pad[(ct * 16 + rr) * 32 + q * 8];
            f32x4 z = {0.f, 0.f, 0.f, 0.f};
            hacc[ct] = __builtin_amdgcn_mfma_f32_16x16x32_bf16(aW, a1, z, 0, 0, 0);
        }
        __builtin_amdgcn_s_setprio(0);
        float s = 0.f, z2 = 0.f;
        #pragma unroll
        for (int ct = 0; ct < 16; ++ct) {
            #pragma unroll
            for (int j = 0; j < 4; ++j) { float v = hacc[ct][j]; s += v; z2 += v * v; }
        }
        s  += __shfl_xor(s, 16);  s  += __shfl_xor(s, 32);
        z2 += __shfl_xor(z2, 16); z2 += __shfl_xor(z2, 32);
        float mean = s * (1.f / 256.f);
        float var = fmaxf(z2 * (1.f / 256.f) - mean * mean, 0.f);
        float rstd = 1.0f / sqrtf(var + 1e-5f);

        uint2 pk[16];
        #pragma unroll
        for (int ct = 0; ct < 16; ++ct) {
            const int c0 = ct * 16 + 4 * q;
            float4 gg = *(const float4*)&g1[c0];
            float4 bb = *(const float4*)&b1[c0];
            float v0 = (hacc[ct][0] - mean) * rstd * gg.x + bb.x;
            float v1 = (hacc[ct][1] - mean) * rstd * gg.y + bb.y;
            float v2 = (hacc[ct][2] - mean) * rstd * gg.z + bb.z;
            float v3 = (hacc[ct][3] - mean) * rstd * gg.w + bb.w;
            v0 = v0 > 0.f ? v0 : 0.1f * v0;
            v1 = v1 > 0.f ? v1 : 0.1f * v1;
            v2 = v2 > 0.f ? v2 : 0.1f * v2;
            v3 = v3 > 0.f ? v3 : 0.1f * v3;
            pk[ct].x = (u32)f2bf(v0) | ((u32)f2bf(v1) << 16);
            pk[ct].y = (u32)f2bf(v2) | ((u32)f2bf(v3) << 16);
        }
        #pragma unroll
        for (int kt = 0; kt < 8; ++kt)
            hfrag[rt][kt] = fixup_frag(pk, kt, srcA, srcB, hiT);
    }
    __syncthreads();   // Bs eighth 0 + idxs ready

    const int ppt = lane >> 5, cl = lane & 31;
    const int* ixp = idxs[2 * w + ppt];

    // GEMM on eighth e: 2 cout-tiles x K=256 -> posw (cols = cout - e*32)
    auto do_gemm = [&]() {
        __builtin_amdgcn_s_setprio(1);
        #pragma unroll
        for (int nt2 = 0; nt2 < 2; ++nt2) {
            f32x4 a0 = {0.f,0.f,0.f,0.f}, a1v = {0.f,0.f,0.f,0.f};
            #pragma unroll
            for (int kb = 0; kb < 8; ++kb) {
                bf16x8 bb = *(const bf16x8*)&Bs[(nt2 * 16 + rr) * 264 + kb * 32 + q * 8];
                a0  = __builtin_amdgcn_mfma_f32_16x16x32_bf16(hfrag[0][kb], bb, a0, 0, 0, 0);
                a1v = __builtin_amdgcn_mfma_f32_16x16x32_bf16(hfrag[1][kb], bb, a1v, 0, 0, 0);
            }
            #pragma unroll
            for (int j = 0; j < 4; ++j) {
                posw[w][0][4 * q + j][nt2 * 16 + rr] = f2bf(a0[j]);
                posw[w][1][4 * q + j][nt2 * 16 + rr] = f2bf(a1v[j]);
            }
        }
        __builtin_amdgcn_s_setprio(0);
    };
    auto stage_e = [&](int en) {
        const char* src = (const char*)(ew2tp + (size_t)en * 32 * 264);
        for (int o = tid * 16; o < 16896; o += 8192)
            *(uint4*)((char*)Bs + o) = *(const uint4*)(src + o);
    };
    auto load_pair = [&](int pi, u32 (&xv)[16]) {   // couts 64*pi .. +63
        const int cq = pi * 64 + cl * 2;
        #pragma unroll
        for (int k = 0; k < 16; ++k)
            xv[k] = *(const u32*)(xcur + (size_t)ixp[k] * 256 + cq);
    };
    auto pool_e = [&](int e, const u32 (&xv)[16]) { // active half-lanes only
        if ((cl >> 4) == (e & 1)) {
            const int t2 = (cl & 15) * 2;
            float m0 = -3e38f, m1 = -3e38f;
            #pragma unroll
            for (int k = 0; k < 16; ++k) {
                u32 pv = *(const u32*)&posw[w][ppt][k][t2];
                m0 = fmaxf(m0, bf2f((u16)(pv & 0xffffu)) + bf2f((u16)(xv[k] & 0xffffu)));
                m1 = fmaxf(m1, bf2f((u16)(pv >> 16))     + bf2f((u16)(xv[k] >> 16)));
            }
            *(u32*)&pbounce[w][ppt][(e >> 1) * 64 + cl * 2] =
                (u32)f2bf(m0) | ((u32)f2bf(m1) << 16);
        }
    };

    bf16x8 gA0[2], gA1[2];
    u32 xv[16];

    // ===== eighth 0 (couts 0-31) =====
    do_gemm();
    __syncthreads();
    stage_e(1);
    #pragma unroll
    for (int pt = 0; pt < 2; ++pt) {      // gA0: pos+x for couts 0..31
        const u16* xr = xcur + (size_t)idxs[2 * w + pt][rr] * 256;
        bf16x8 xa = *(const bf16x8*)(xr + q * 8);
        bf16x8 pv = *(const bf16x8*)&posw[w][pt][rr][q * 8];
        bf16x8 g;
        #pragma unroll
        for (int e = 0; e < 8; ++e)
            g[e] = (short)f2bf(bf2f((u16)xa[e]) + bf2f((u16)pv[e]));
        gA0[pt] = g;
    }
    __syncthreads();

    // ===== eighth 1 (couts 32-63) =====
    do_gemm();
    __syncthreads();
    stage_e(2);
    #pragma unroll
    for (int pt = 0; pt < 2; ++pt) {      // gA1 + conv + pbounce couts 0..63
        const u16* xr = xcur + (size_t)idxs[2 * w + pt][rr] * 256;
        bf16x8 xa = *(const bf16x8*)(xr + 32 + q * 8);
        bf16x8 pv = *(const bf16x8*)&posw[w][pt][rr][q * 8];
        bf16x8 g;
        #pragma unroll
        for (int e = 0; e < 8; ++e)
            g[e] = (short)f2bf(bf2f((u16)xa[e]) + bf2f((u16)pv[e]));
        gA1[pt] = g;
    }
    #pragma unroll
    for (int pt = 0; pt < 2; ++pt) {
        __builtin_amdgcn_s_setprio(1);
        #pragma unroll
        for (int cn = 0; cn < 4; ++cn) {
            bf16x8 cB0 = *(const bf16x8*)&convbf[(cn * 16 + rr) * 64 + q * 8];
            bf16x8 cB1 = *(const bf16x8*)&convbf[(cn * 16 + rr) * 64 + 32 + q * 8];
            f32x4 z = {0.f,0.f,0.f,0.f};
            f32x4 acc = __builtin_amdgcn_mfma_f32_16x16x32_bf16(gA0[pt], cB0, z, 0, 0, 0);
            acc = __builtin_amdgcn_mfma_f32_16x16x32_bf16(gA1[pt], cB1, acc, 0, 0, 0);
            float m = fmaxf(fmaxf(acc[0], acc[1]), fmaxf(acc[2], acc[3]));
            m = fmaxf(m, __shfl_xor(m, 16));
            m = fmaxf(m, __shfl_xor(m, 32));
            if (lane < 16) pbounce[w][pt][cn * 16 + lane] = f2bf(m);
        }
        __builtin_amdgcn_s_setprio(0);
    }
    load_pair(1, xv);
    __syncthreads();

    // ===== eighths 2..7 =====
    do_gemm();                 // e2
    __syncthreads();
    stage_e(3);
    pool_e(2, xv);
    __syncthreads();

    do_gemm();                 // e3
    __syncthreads();
    stage_e(4);
    pool_e(3, xv);
    load_pair(2, xv);
    __syncthreads();

    do_gemm();                 // e4
    __syncthreads();
    stage_e(5);
    pool_e(4, xv);
    __syncthreads();

    do_gemm();                 // e5
    __syncthreads();
    stage_e(6);
    pool_e(5, xv);
    load_pair(3, xv);
    __syncthreads();

    do_gemm();                 // e6
    __syncthreads();
    stage_e(7);
    pool_e(6, xv);
    __syncthreads();

    do_gemm();                 // e7
    pool_e(7, xv);

    // one-shot contiguous pooled write (512 B per point)
    {
        const int pt = lane >> 5, off = (lane & 31) * 8;
        uint4 v = *(const uint4*)&pbounce[w][pt][off];
        *(uint4*)(pooledb + (size_t)(i0 + 2 * w + pt) * 256 + off) = v;
    }
}

// ---------- pointwise v7: bf16 I/O + s_setprio around GEMM clusters. (R11 verbatim)
__global__ __launch_bounds__(512, 4) void k_pointwise(
    const u16* poolb,
    const u16* __restrict__ xresb,
    u16*       outb,
    const u16* __restrict__ b1t,
    const float* __restrict__ g1, const float* __restrict__ b1,
    const u16* __restrict__ b2t,
    const float* __restrict__ g2, const float* __restrict__ b2,
    int guardRes)
{
    __shared__ u16 hm[32 * 1032];
    __shared__ float pst[32][8][2];

    const int tid = threadIdx.x, w = tid >> 6, lane = tid & 63;
    const int rr = lane & 15, q = lane >> 4;
    const size_t R0 = (size_t)blockIdx.x * 32;

    bf16x8 afr[2][8];
    #pragma unroll
    for (int rt = 0; rt < 2; ++rt) {
        int ar = (int)R0 + rt * 16 + rr; if (ar >= N_PTS) ar = N_PTS - 1;
        const u16* arow = poolb + (size_t)ar * 256;
        #pragma unroll
        for (int kb = 0; kb < 8; ++kb)
            afr[rt][kb] = *(const bf16x8*)(arow + kb * 32 + q * 8);
    }

    #pragma unroll 2
    for (int ct = 0; ct < 8; ++ct) {
        const int co = w * 128 + ct * 16 + rr;
        const u16* bp = b1t + (size_t)co * 256 + q * 8;
        bf16x8 bb[8];
        #pragma unroll
        for (int kb = 0; kb < 8; ++kb) bb[kb] = *(const bf16x8*)(bp + kb * 32);
        f32x4 a0 = {0.f,0.f,0.f,0.f}, a1v = {0.f,0.f,0.f,0.f};
        __builtin_amdgcn_s_setprio(1);
        #pragma unroll
        for (int kb = 0; kb < 8; ++kb) {
            a0  = __builtin_amdgcn_mfma_f32_16x16x32_bf16(afr[0][kb], bb[kb], a0, 0, 0, 0);
            a1v = __builtin_amdgcn_mfma_f32_16x16x32_bf16(afr[1][kb], bb[kb], a1v, 0, 0, 0);
        }
        __builtin_amdgcn_s_setprio(0);
        #pragma unroll
        for (int j = 0; j < 4; ++j) {
            hm[(4 * q + j) * 1032 + co]      = f2bf(a0[j]);
            hm[(16 + 4 * q + j) * 1032 + co] = f2bf(a1v[j]);
        }
    }
    __syncthreads();

    {
        const int row = tid >> 4;
        const int t16 = tid & 15;
        u32* hm32 = (u32*)hm;
        const int base = row * 516;
        float s = 0.f, z = 0.f;
        #pragma unroll 8
        for (int e = 0; e < 32; ++e) {
            u32 pk = hm32[base + t16 + 16 * e];
            float v0 = bf2f((u16)(pk & 0xffffu)), v1 = bf2f((u16)(pk >> 16));
            s += v0 + v1; z += v0 * v0 + v1 * v1;
        }
        s += __shfl_xor(s, 1); s += __shfl_xor(s, 2);
        s += __shfl_xor(s, 4); s += __shfl_xor(s, 8);
        z += __shfl_xor(z, 1); z += __shfl_xor(z, 2);
        z += __shfl_xor(z, 4); z += __shfl_xor(z, 8);
        float mean = s * (1.f / 1024.f);
        float var = fmaxf(z * (1.f / 1024.f) - mean * mean, 0.f);
        float rstd = 1.0f / sqrtf(var + 1e-5f);
        #pragma unroll 4
        for (int e = 0; e < 32; ++e) {
            const int cidx = t16 + 16 * e;
            u32 pk = hm32[base + cidx];
            const int c = cidx * 2;
            float2 gg = *(const float2*)&g1[c];
            float2 bbv = *(const float2*)&b1[c];
            float v0 = (bf2f((u16)(pk & 0xffffu)) - mean) * rstd * gg.x + bbv.x;
            float v1 = (bf2f((u16)(pk >> 16))     - mean) * rstd * gg.y + bbv.y;
            v0 = v0 > 0.f ? v0 : 0.1f * v0;
            v1 = v1 > 0.f ? v1 : 0.1f * v1;
            hm32[base + cidx] = (u32)f2bf(v0) | ((u32)f2bf(v1) << 16);
        }
    }
    __syncthreads();

    f32x4 acc2[2][2];
    #pragma unroll
    for (int ct = 0; ct < 2; ++ct) {
        const int cB = w * 32 + ct * 16 + rr;
        const u16* bp = b2t + (size_t)cB * 1024 + q * 8;
        f32x4 c0 = {0.f,0.f,0.f,0.f}, c1 = {0.f,0.f,0.f,0.f};
        __builtin_amdgcn_s_setprio(1);
        #pragma unroll 8
        for (int kb = 0; kb < 32; ++kb) {
            bf16x8 b  = *(const bf16x8*)(bp + kb * 32);
            bf16x8 a0 = *(const bf16x8*)&hm[rr * 1032 + kb * 32 + q * 8];
            bf16x8 a1 = *(const bf16x8*)&hm[(16 + rr) * 1032 + kb * 32 + q * 8];
            c0 = __builtin_amdgcn_mfma_f32_16x16x32_bf16(a0, b, c0, 0, 0, 0);
            c1 = __builtin_amdgcn_mfma_f32_16x16x32_bf16(a1, b, c1, 0, 0, 0);
        }
        __builtin_amdgcn_s_setprio(0);
        acc2[0][ct] = c0; acc2[1][ct] = c1;
    }

    #pragma unroll
    for (int rt = 0; rt < 2; ++rt) {
        #pragma unroll
        for (int j = 0; j < 4; ++j) {
            float s = acc2[rt][0][j] + acc2[rt][1][j];
            float z = acc2[rt][0][j] * acc2[rt][0][j] + acc2[rt][1][j] * acc2[rt][1][j];
            s += __shfl_xor(s, 1); s += __shfl_xor(s, 2);
            s += __shfl_xor(s, 4); s += __shfl_xor(s, 8);
            z += __shfl_xor(z, 1); z += __shfl_xor(z, 2);
            z += __shfl_xor(z, 4); z += __shfl_xor(z, 8);
            if (rr == 0) {
                pst[rt * 16 + 4 * q + j][w][0] = s;
                pst[rt * 16 + 4 * q + j][w][1] = z;
            }
        }
    }
    __syncthreads();

    #pragma unroll
    for (int rt = 0; rt < 2; ++rt) {
        float mean2[4], rstd2[4];
        #pragma unroll
        for (int j = 0; j < 4; ++j) {
            const int row = rt * 16 + 4 * q + j;
            float s = 0.f, z = 0.f;
            #pragma unroll
            for (int k = 0; k < 8; ++k) { s += pst[row][k][0]; z += pst[row][k][1]; }
            float mean = s * (1.f / 256.f);
            float var = fmaxf(z * (1.f / 256.f) - mean * mean, 0.f);
            mean2[j] = mean;
            rstd2[j] = 1.0f / sqrtf(var + 1e-5f);
        }
        #pragma unroll
        for (int ct = 0; ct < 2; ++ct) {
            const int c = w * 32 + ct * 16 + rr;
            const float gg = g2[c], bb = b2[c];
            #pragma unroll
            for (int j = 0; j < 4; ++j) {
                const size_t row = R0 + rt * 16 + 4 * q + j;
                float v = (acc2[rt][ct][j] - mean2[j]) * rstd2[j] * gg + bb;
                float xv = 0.f;
                if (!guardRes || row < (size_t)N_PTS) xv = bf2f(xresb[row * 256 + c]);
                float o = v + xv;
                outb[row * 256 + c] = f2bf(o > 0.f ? o : 0.f);
            }
        }
    }
}

// ---------- final projection: bf16 input, B staged in LDS halves (R11 verbatim)
__global__ __launch_bounds__(512, 4) void k_proj(
    const u16*   __restrict__ xinb,
    const u16*   __restrict__ pjtp,
    const float* __restrict__ pb,
    float*       __restrict__ out)
{
    __shared__ u16 Bs[128 * 264];
    const int tid = threadIdx.x, w = tid >> 6, lane = tid & 63;
    const int rr = lane & 15, q = lane >> 4;
    const size_t R0 = (size_t)blockIdx.x * 128 + (size_t)w * 16;

    int arn = (int)R0 + rr; if (arn >= N_PTS) arn = N_PTS - 1;
    const u16* arow = xinb + (size_t)arn * 256;
    bf16x8 afr[8];
    #pragma unroll
    for (int kb = 0; kb < 8; ++kb)
        afr[kb] = *(const bf16x8*)(arow + kb * 32 + q * 8);

    #pragma unroll 1
    for (int h = 0; h < 2; ++h) {
        if (h) __syncthreads();
        for (int o = tid * 16; o < 67584; o += 8192)
            *(uint4*)((char*)Bs + o) = *(const uint4*)((const char*)(pjtp + h * 128 * 264) + o);
        __syncthreads();
        #pragma unroll 2
        for (int nt8 = 0; nt8 < 8; ++nt8) {
            f32x4 acc = {0.f, 0.f, 0.f, 0.f};
            __builtin_amdgcn_s_setprio(1);
            #pragma unroll
            for (int kb = 0; kb < 8; ++kb) {
                bf16x8 b = *(const bf16x8*)&Bs[(nt8 * 16 + rr) * 264 + kb * 32 + q * 8];
                acc = __builtin_amdgcn_mfma_f32_16x16x32_bf16(afr[kb], b, acc, 0, 0, 0);
            }
            __builtin_amdgcn_s_setprio(0);
            const int c = h * 128 + nt8 * 16 + rr;
            const float bias = pb[c];
            #pragma unroll
            for (int j = 0; j < 4; ++j) {
                const size_t row = R0 + 4 * q + j;
                if (row < (size_t)N_PTS) out[row * 256 + c] = acc[j] + bias;
            }
        }
    }
}

extern "C" void kernel_launch(void* const* d_in, const int* in_sizes, int n_in,
                              void* d_out, int out_size, void* d_ws, size_t ws_size,
                              hipStream_t stream) {
    const float* p      = (const float*)d_in[0];
    const float* x      = (const float*)d_in[1];
    const float* nn     = (const float*)d_in[2];
    const int*   idx    = (const int*)d_in[3];
    const float* r      = (const float*)d_in[4];
    const float* emb_w1 = (const float*)d_in[5];
    const float* emb_g1 = (const float*)d_in[6];
    const float* emb_b1 = (const float*)d_in[7];
    const float* emb_w2 = (const float*)d_in[8];
    const float* conv_w = (const float*)d_in[9];
    const float* pw_w1  = (const float*)d_in[10];
    const float* pw_g1  = (const float*)d_in[11];
    const float* pw_b1  = (const float*)d_in[12];
    const float* pw_w2  = (const float*)d_in[13];
    const float* pw_g2  = (const float*)d_in[14];
    const float* pw_b2  = (const float*)d_in[15];
    const float* proj_w = (const float*)d_in[16];
    const float* proj_b = (const float*)d_in[17];
    float* out = (float*)d_out;

    char* ws = (char*)d_ws;
    const size_t SZB = (size_t)NPAD * 256 * sizeof(u16);   // 51.2 MB
    u16* xb0 = (u16*)ws;                   // bf16(x) / L1 pooled
    u16* PB  = (u16*)(ws + SZB);           // L0 pooled / L1 output
    u16* h1B = (u16*)(ws + 2 * SZB);       // L0 output (gather src + residual for L1)
    u16* f5b = (u16*)(ws + 3 * SZB);       // [N][16][5] bf16, 16 MB
    u16* wb  = f5b + (size_t)N_PTS * 16 * 5;
    u16* ew2tp  = wb;                      // [2][256][264]
    u16* pjtp   = ew2tp + 2 * 256 * 264;   // [256][264]
    u16* w1pad  = pjtp + 256 * 264;        // [2][256][32]
    u16* convbf = w1pad + 2 * 256 * 32;    // [2][64][64]
    u16* b1t    = convbf + 2 * 64 * 64;    // [2][1024][256]
    u16* b2t    = b1t + 2 * 1024 * 256;    // [2][256][1024]

    k_transpose_pad<<<(2*256*264 + 255)/256, 256, 0, stream>>>(emb_w2, ew2tp, 2, 256, 256, 264);
    k_transpose_pad<<<(256*264 + 255)/256, 256, 0, stream>>>(proj_w, pjtp, 1, 256, 256, 264);
    k_transpose_pad<<<(2*256*32 + 255)/256, 256, 0, stream>>>(emb_w1, w1pad, 2, 5, 256, 32);
    k_transpose_pad<<<(2*1024*256 + 255)/256, 256, 0, stream>>>(pw_w1, b1t, 2, 256, 1024, 256);
    k_transpose_pad<<<(2*256*1024 + 255)/256, 256, 0, stream>>>(pw_w2, b2t, 2, 1024, 256, 1024);
    k_cast_bf16<<<(2*64*64 + 255)/256, 256, 0, stream>>>(conv_w, convbf, 2*64*64);

    k_castx8<<<(N_PTS*256/8 + 255)/256, 256, 0, stream>>>(x, xb0, N_PTS*256/8);
    k_ppf<<<(N_PTS * 16 + 255)/256, 256, 0, stream>>>(p, nn, idx, r, f5b);

    // layer 0
    k_neighbor<<<N_PTS/16, 512, 0, stream>>>(xb0, f5b, idx, w1pad, emb_g1, emb_b1,
                                             ew2tp, convbf, PB);
    k_pointwise<<<NPAD/32, 512, 0, stream>>>(PB, xb0, h1B, b1t, pw_g1, pw_b1,
                                             b2t, pw_g2, pw_b2, 1);
    // layer 1
    k_neighbor<<<N_PTS/16, 512, 0, stream>>>(h1B, f5b, idx, w1pad + 256*32,
                                             emb_g1 + 256, emb_b1 + 256,
                                             ew2tp + 256*264, convbf + 64*64, xb0);
    k_pointwise<<<NPAD/32, 512, 0, stream>>>(xb0, h1B, PB, b1t + 1024*256,
                                             pw_g1 + 1024, pw_b1 + 1024,
                                             b2t + 256*1024, pw_g2 + 256, pw_b2 + 256, 0);
    // projection
    k_proj<<<(NPAD + 127)/128, 512, 0, stream>>>(PB, pjtp, proj_b, out);
}

// Round 13
// 2123.229 us; speedup vs baseline: 1.1947x; 1.1947x over previous
//
#include <hip/hip_runtime.h>
#include <hip/hip_bf16.h>
#include <stdint.h>

#define N_PTS 100000
#define NPAD  100032   // 64-divisible

typedef unsigned short u16;
typedef unsigned int   u32;
using bf16x8 = __attribute__((ext_vector_type(8))) short;
using f32x4  = __attribute__((ext_vector_type(4))) float;

// RNE f32->bf16 via the compiler's native conversion (1-2 VALU ops, pairable)
__device__ __forceinline__ u16 f2bf(float f) {
    __hip_bfloat16 h = __float2bfloat16(f);
    return *reinterpret_cast<u16*>(&h);
}
__device__ __forceinline__ float bf2f(u16 h) {
    return __uint_as_float(((u32)h) << 16);
}

// ---------- padded transpose to bf16: dst[l][co][stride] = src[l][ci][co] (ci<R else 0)
__global__ __launch_bounds__(256) void k_transpose_pad(
    const float* __restrict__ src, u16* __restrict__ dst,
    int Lc, int R, int Cc, int stride) {
    int t = blockIdx.x * 256 + threadIdx.x;
    int total = Lc * Cc * stride;
    if (t >= total) return;
    int l = t / (Cc * stride);
    int rem = t - l * (Cc * stride);
    int co = rem / stride;
    int ci = rem - co * stride;
    dst[t] = (ci < R) ? f2bf(src[((size_t)l * R + ci) * Cc + co]) : (u16)0;
}

__global__ __launch_bounds__(256) void k_cast_bf16(
    const float* __restrict__ src, u16* __restrict__ dst, int total) {
    int t = blockIdx.x * 256 + threadIdx.x;
    if (t < total) dst[t] = f2bf(src[t]);
}

// vectorized fp32 -> bf16 cast, 8 elements/thread
__global__ __launch_bounds__(256) void k_castx8(
    const float* __restrict__ src, u16* __restrict__ dst, int total8) {
    int t = blockIdx.x * 256 + threadIdx.x;
    if (t >= total8) return;
    float4 a = *(const float4*)(src + (size_t)t * 8);
    float4 b = *(const float4*)(src + (size_t)t * 8 + 4);
    uint4 o;
    o.x = (u32)f2bf(a.x) | ((u32)f2bf(a.y) << 16);
    o.y = (u32)f2bf(a.z) | ((u32)f2bf(a.w) << 16);
    o.z = (u32)f2bf(b.x) | ((u32)f2bf(b.y) << 16);
    o.w = (u32)f2bf(b.z) | ((u32)f2bf(b.w) << 16);
    *(uint4*)(dst + (size_t)t * 8) = o;
}

// ---------- PPF features (bf16 output)
__device__ __forceinline__ float angf(float ax, float ay, float az,
                                      float bx, float by, float bz) {
    float cx = ay * bz - az * by;
    float cy = az * bx - ax * bz;
    float cz = ax * by - ay * bx;
    float cr = sqrtf(cx * cx + cy * cy + cz * cz);
    float dt = ax * bx + ay * by + az * bz;
    return atan2f(cr, dt);
}

__global__ __launch_bounds__(256) void k_ppf(
    const float* __restrict__ p, const float* __restrict__ nrm,
    const int* __restrict__ idx, const float* __restrict__ r,
    u16* __restrict__ f5b) {
    int t = blockIdx.x * 256 + threadIdx.x;
    if (t >= N_PTS * 16) return;
    int i = t >> 4;
    int j = idx[(size_t)i * 32 + (t & 15)];
    float pix = p[(size_t)i*3], piy = p[(size_t)i*3+1], piz = p[(size_t)i*3+2];
    float pjx = p[(size_t)j*3], pjy = p[(size_t)j*3+1], pjz = p[(size_t)j*3+2];
    float dx = pjx - pix, dy = pjy - piy, dz = pjz - piz;
    float dist = sqrtf(dx*dx + dy*dy + dz*dz);
    float nix = nrm[(size_t)i*3], niy = nrm[(size_t)i*3+1], niz = nrm[(size_t)i*3+2];
    float njx = nrm[(size_t)j*3], njy = nrm[(size_t)j*3+1], njz = nrm[(size_t)j*3+2];
    float a1 = angf(nix, niy, niz, dx, dy, dz);
    float a2 = angf(njx, njy, njz, dx, dy, dz);
    float a3 = angf(nix, niy, niz, njx, njy, njz);
    float rinv = 1.0f / r[0];
    u16* o = f5b + (size_t)t * 5;
    o[0] = f2bf(a1); o[1] = f2bf(a2); o[2] = f2bf(a3);
    o[3] = f2bf(dist); o[4] = f2bf(dist * rinv);
}

// Build an h A-fragment (m = neighbor rr, k = couts) from swapped-emb D-tiles.
__device__ __forceinline__ bf16x8 fixup_frag(const uint2* pk, int kt,
                                             int srcA, int srcB, bool hiT) {
    int aLx = __shfl((int)pk[2*kt].x,   srcA);
    int aHx = __shfl((int)pk[2*kt+1].x, srcA);
    int aLy = __shfl((int)pk[2*kt].y,   srcA);
    int aHy = __shfl((int)pk[2*kt+1].y, srcA);
    int bLx = __shfl((int)pk[2*kt].x,   srcB);
    int bHx = __shfl((int)pk[2*kt+1].x, srcB);
    int bLy = __shfl((int)pk[2*kt].y,   srcB);
    int bHy = __shfl((int)pk[2*kt+1].y, srcB);
    uint4 u;
    u.x = (u32)(hiT ? aHx : aLx);
    u.y = (u32)(hiT ? aHy : aLy);
    u.z = (u32)(hiT ? bHx : bLx);
    u.w = (u32)(hiT ? bHy : bLy);
    return *(bf16x8*)&u;
}

// ---------- neighbor stage v11 (R11 structure): R8 access patterns + setprio.
// 16 pts/block, 512 thr, 8 waves, wave = 2 pts. LDS 78 KB -> 2 blocks/CU.
__global__ __launch_bounds__(512, 4) void k_neighbor(
    const u16*   __restrict__ xcur,   // [*][256] bf16 gather source
    const u16*   __restrict__ f5b,    // [N][16][5] bf16
    const int*   __restrict__ idx,
    const u16*   __restrict__ w1pad,  // [256][32]
    const float* __restrict__ g1, const float* __restrict__ b1,
    const u16*   __restrict__ ew2tp,  // [256][264]
    const u16*   __restrict__ convbf, // [64][64]
    u16*         __restrict__ pooledb)// [NPAD][256] bf16
{
    __shared__ u16 Bs[64 * 264];           // 33,792 B: one 64-cout quarter
    __shared__ u16 posw[8][2][16][72];     // 36,864 B: per-wave pos (bf16, padded)
    __shared__ u16 pbounce[8][2][256];     //  8,192 B: per-wave pooled rows
    __shared__ int idxs[16][16];           //  1,024 B

    const int tid = threadIdx.x, w = tid >> 6, lane = tid & 63;
    const int rr = lane & 15, q = lane >> 4;
    const int i0 = blockIdx.x * 16;

    // stage quarter 0 + idxs (overlaps emb compute)
    for (int o = tid * 16; o < 33792; o += 8192)
        *(uint4*)((char*)Bs + o) = *(const uint4*)((const char*)ew2tp + o);
    if (tid < 256)
        idxs[tid >> 4][tid & 15] = idx[(size_t)(i0 + (tid >> 4)) * 32 + (tid & 15)];

    const int srcA = rr + ((q & 1) << 5);
    const int srcB = srcA + 16;
    const bool hiT = (q >> 1) != 0;

    // ---- emb (swapped): lane rr = neighbor, in-lane couts; LN; fixup -> hfrag ----
    bf16x8 hfrag[2][8];
    #pragma unroll
    for (int rt = 0; rt < 2; ++rt) {
        const int pt = i0 + 2 * w + rt;
        bf16x8 a1;
        #pragma unroll
        for (int e = 0; e < 8; ++e) a1[e] = 0;
        if (q == 0) {
            const u16* fp = f5b + (size_t)(pt * 16 + rr) * 5;
            a1[0] = (short)fp[0]; a1[1] = (short)fp[1];
            a1[2] = (short)fp[2]; a1[3] = (short)fp[3];
            a1[4] = (short)fp[4];
        }
        f32x4 hacc[16];
        __builtin_amdgcn_s_setprio(1);
        #pragma unroll
        for (int ct = 0; ct < 16; ++ct) {
            bf16x8 aW = *(const bf16x8*)&w1pad[(ct * 16 + rr) * 32 + q * 8];
            f32x4 z = {0.f, 0.f, 0.f, 0.f};
            hacc[ct] = __builtin_amdgcn_mfma_f32_16x16x32_bf16(aW, a1, z, 0, 0, 0);
        }
        __builtin_amdgcn_s_setprio(0);
        float s = 0.f, z2 = 0.f;
        #pragma unroll
        for (int ct = 0; ct < 16; ++ct) {
            #pragma unroll
            for (int j = 0; j < 4; ++j) { float v = hacc[ct][j]; s += v; z2 += v * v; }
        }
        s  += __shfl_xor(s, 16);  s  += __shfl_xor(s, 32);
        z2 += __shfl_xor(z2, 16); z2 += __shfl_xor(z2, 32);
        float mean = s * (1.f / 256.f);
        float var = fmaxf(z2 * (1.f / 256.f) - mean * mean, 0.f);
        float rstd = 1.0f / sqrtf(var + 1e-5f);

        uint2 pk[16];
        #pragma unroll
        for (int ct = 0; ct < 16; ++ct) {
            const int c0 = ct * 16 + 4 * q;
            float4 gg = *(const float4*)&g1[c0];
            float4 bb = *(const float4*)&b1[c0];
            float v0 = (hacc[ct][0] - mean) * rstd * gg.x + bb.x;
            float v1 = (hacc[ct][1] - mean) * rstd * gg.y + bb.y;
            float v2 = (hacc[ct][2] - mean) * rstd * gg.z + bb.z;
            float v3 = (hacc[ct][3] - mean) * rstd * gg.w + bb.w;
            v0 = v0 > 0.f ? v0 : 0.1f * v0;
            v1 = v1 > 0.f ? v1 : 0.1f * v1;
            v2 = v2 > 0.f ? v2 : 0.1f * v2;
            v3 = v3 > 0.f ? v3 : 0.1f * v3;
            pk[ct].x = (u32)f2bf(v0) | ((u32)f2bf(v1) << 16);
            pk[ct].y = (u32)f2bf(v2) | ((u32)f2bf(v3) << 16);
        }
        #pragma unroll
        for (int kt = 0; kt < 8; ++kt)
            hfrag[rt][kt] = fixup_frag(pk, kt, srcA, srcB, hiT);
    }
    __syncthreads();   // Bs quarter 0 + idxs ready

    const int ppt = lane >> 5, cl = lane & 31;
    const int* ixp = idxs[2 * w + ppt];

    #pragma unroll 1
    for (int p = 0; p < 4; ++p) {
        // ---- main GEMM on quarter p: 4 cout-tiles x K=256 -> posw ----
        __builtin_amdgcn_s_setprio(1);
        #pragma unroll
        for (int nt4 = 0; nt4 < 4; ++nt4) {
            f32x4 a0 = {0.f,0.f,0.f,0.f}, a1v = {0.f,0.f,0.f,0.f};
            #pragma unroll
            for (int kb = 0; kb < 8; ++kb) {
                bf16x8 bb = *(const bf16x8*)&Bs[(nt4 * 16 + rr) * 264 + kb * 32 + q * 8];
                a0  = __builtin_amdgcn_mfma_f32_16x16x32_bf16(hfrag[0][kb], bb, a0, 0, 0, 0);
                a1v = __builtin_amdgcn_mfma_f32_16x16x32_bf16(hfrag[1][kb], bb, a1v, 0, 0, 0);
            }
            #pragma unroll
            for (int j = 0; j < 4; ++j) {
                posw[w][0][4 * q + j][nt4 * 16 + rr] = f2bf(a0[j]);
                posw[w][1][4 * q + j][nt4 * 16 + rr] = f2bf(a1v[j]);
            }
        }
        __builtin_amdgcn_s_setprio(0);
        if (p < 3) {
            __syncthreads();   // all waves done reading Bs quarter p
            const char* src = (const char*)(ew2tp + (size_t)(p + 1) * 64 * 264);
            for (int o = tid * 16; o < 33792; o += 8192)
                *(uint4*)((char*)Bs + o) = *(const uint4*)(src + o);
        }
        // ---- post-pass (no Bs use; overlaps the restage) ----
        if (p == 0) {
            // conv on couts 0..63: 128B/row bf16 gathers; result -> pbounce
            #pragma unroll
            for (int pt = 0; pt < 2; ++pt) {
                const u16* xr = xcur + (size_t)idxs[2 * w + pt][rr] * 256;
                bf16x8 gA[2];
                #pragma unroll
                for (int kb = 0; kb < 2; ++kb) {
                    bf16x8 xa = *(const bf16x8*)(xr + kb * 32 + q * 8);
                    bf16x8 pv = *(const bf16x8*)&posw[w][pt][rr][kb * 32 + q * 8];
                    bf16x8 g;
                    #pragma unroll
                    for (int e = 0; e < 8; ++e)
                        g[e] = (short)f2bf(bf2f((u16)xa[e]) + bf2f((u16)pv[e]));
                    gA[kb] = g;
                }
                __builtin_amdgcn_s_setprio(1);
                #pragma unroll
                for (int cn = 0; cn < 4; ++cn) {
                    bf16x8 cB0 = *(const bf16x8*)&convbf[(cn * 16 + rr) * 64 + q * 8];
                    bf16x8 cB1 = *(const bf16x8*)&convbf[(cn * 16 + rr) * 64 + 32 + q * 8];
                    f32x4 z = {0.f,0.f,0.f,0.f};
                    f32x4 acc = __builtin_amdgcn_mfma_f32_16x16x32_bf16(gA[0], cB0, z, 0, 0, 0);
                    acc = __builtin_amdgcn_mfma_f32_16x16x32_bf16(gA[1], cB1, acc, 0, 0, 0);
                    float m = fmaxf(fmaxf(acc[0], acc[1]), fmaxf(acc[2], acc[3]));
                    m = fmaxf(m, __shfl_xor(m, 16));
                    m = fmaxf(m, __shfl_xor(m, 32));
                    if (lane < 16) pbounce[w][pt][cn * 16 + lane] = f2bf(m);
                }
                __builtin_amdgcn_s_setprio(0);
            }
        } else {
            // direct pooling: lane covers 2 couts; 128B/row bf16 gathers (hoisted)
            const int cq = p * 64 + cl * 2;
            u32 xv[16];
            #pragma unroll
            for (int k = 0; k < 16; ++k)
                xv[k] = *(const u32*)(xcur + (size_t)ixp[k] * 256 + cq);
            float m0 = -3e38f, m1 = -3e38f;
            #pragma unroll
            for (int k = 0; k < 16; ++k) {
                u32 pv = *(const u32*)&posw[w][ppt][k][cl * 2];
                float gv0 = bf2f((u16)(pv & 0xffffu)) + bf2f((u16)(xv[k] & 0xffffu));
                float gv1 = bf2f((u16)(pv >> 16))     + bf2f((u16)(xv[k] >> 16));
                m0 = fmaxf(m0, gv0);
                m1 = fmaxf(m1, gv1);
            }
            *(u32*)&pbounce[w][ppt][cq] = (u32)f2bf(m0) | ((u32)f2bf(m1) << 16);
        }
        if (p < 3) __syncthreads();   // Bs quarter p+1 ready
    }
    // one-shot contiguous pooled write (512 B per point)
    {
        const int pt = lane >> 5, off = (lane & 31) * 8;
        uint4 v = *(const uint4*)&pbounce[w][pt][off];
        *(uint4*)(pooledb + (size_t)(i0 + 2 * w + pt) * 256 + off) = v;
    }
}

// ---------- pointwise v7: bf16 I/O + s_setprio around GEMM clusters.
__global__ __launch_bounds__(512, 4) void k_pointwise(
    const u16* poolb,                  // [NPAD][256] bf16
    const u16* __restrict__ xresb,     // bf16 residual source
    u16*       outb,                   // [NPAD][256] bf16
    const u16* __restrict__ b1t,       // [1024][256]
    const float* __restrict__ g1, const float* __restrict__ b1,
    const u16* __restrict__ b2t,       // [256][1024]
    const float* __restrict__ g2, const float* __restrict__ b2,
    int guardRes)
{
    __shared__ u16 hm[32 * 1032];      // 66,048 B
    __shared__ float pst[32][8][2];

    const int tid = threadIdx.x, w = tid >> 6, lane = tid & 63;
    const int rr = lane & 15, q = lane >> 4;
    const size_t R0 = (size_t)blockIdx.x * 32;

    bf16x8 afr[2][8];
    #pragma unroll
    for (int rt = 0; rt < 2; ++rt) {
        int ar = (int)R0 + rt * 16 + rr; if (ar >= N_PTS) ar = N_PTS - 1;
        const u16* arow = poolb + (size_t)ar * 256;
        #pragma unroll
        for (int kb = 0; kb < 8; ++kb)
            afr[rt][kb] = *(const bf16x8*)(arow + kb * 32 + q * 8);
    }

    // ---- GEMM1: wave covers cols [w*128, w*128+128), all 32 rows ----
    #pragma unroll 2
    for (int ct = 0; ct < 8; ++ct) {
        const int co = w * 128 + ct * 16 + rr;
        const u16* bp = b1t + (size_t)co * 256 + q * 8;
        bf16x8 bb[8];
        #pragma unroll
        for (int kb = 0; kb < 8; ++kb) bb[kb] = *(const bf16x8*)(bp + kb * 32);
        f32x4 a0 = {0.f,0.f,0.f,0.f}, a1v = {0.f,0.f,0.f,0.f};
        __builtin_amdgcn_s_setprio(1);
        #pragma unroll
        for (int kb = 0; kb < 8; ++kb) {
            a0  = __builtin_amdgcn_mfma_f32_16x16x32_bf16(afr[0][kb], bb[kb], a0, 0, 0, 0);
            a1v = __builtin_amdgcn_mfma_f32_16x16x32_bf16(afr[1][kb], bb[kb], a1v, 0, 0, 0);
        }
        __builtin_amdgcn_s_setprio(0);
        #pragma unroll
        for (int j = 0; j < 4; ++j) {
            hm[(4 * q + j) * 1032 + co]      = f2bf(a0[j]);
            hm[(16 + 4 * q + j) * 1032 + co] = f2bf(a1v[j]);
        }
    }
    __syncthreads();

    // ---- LN1 (read-back stats) + normalize + leaky ----
    {
        const int row = tid >> 4;
        const int t16 = tid & 15;
        u32* hm32 = (u32*)hm;
        const int base = row * 516;
        float s = 0.f, z = 0.f;
        #pragma unroll 8
        for (int e = 0; e < 32; ++e) {
            u32 pk = hm32[base + t16 + 16 * e];
            float v0 = bf2f((u16)(pk & 0xffffu)), v1 = bf2f((u16)(pk >> 16));
            s += v0 + v1; z += v0 * v0 + v1 * v1;
        }
        s += __shfl_xor(s, 1); s += __shfl_xor(s, 2);
        s += __shfl_xor(s, 4); s += __shfl_xor(s, 8);
        z += __shfl_xor(z, 1); z += __shfl_xor(z, 2);
        z += __shfl_xor(z, 4); z += __shfl_xor(z, 8);
        float mean = s * (1.f / 1024.f);
        float var = fmaxf(z * (1.f / 1024.f) - mean * mean, 0.f);
        float rstd = 1.0f / sqrtf(var + 1e-5f);
        #pragma unroll 4
        for (int e = 0; e < 32; ++e) {
            const int cidx = t16 + 16 * e;
            u32 pk = hm32[base + cidx];
            const int c = cidx * 2;
            float2 gg = *(const float2*)&g1[c];
            float2 bbv = *(const float2*)&b1[c];
            float v0 = (bf2f((u16)(pk & 0xffffu)) - mean) * rstd * gg.x + bbv.x;
            float v1 = (bf2f((u16)(pk >> 16))     - mean) * rstd * gg.y + bbv.y;
            v0 = v0 > 0.f ? v0 : 0.1f * v0;
            v1 = v1 > 0.f ? v1 : 0.1f * v1;
            hm32[base + cidx] = (u32)f2bf(v0) | ((u32)f2bf(v1) << 16);
        }
    }
    __syncthreads();

    // ---- GEMM2: wave covers out cols [w*32, w*32+32), K=1024 ----
    f32x4 acc2[2][2];
    #pragma unroll
    for (int ct = 0; ct < 2; ++ct) {
        const int cB = w * 32 + ct * 16 + rr;
        const u16* bp = b2t + (size_t)cB * 1024 + q * 8;
        f32x4 c0 = {0.f,0.f,0.f,0.f}, c1 = {0.f,0.f,0.f,0.f};
        __builtin_amdgcn_s_setprio(1);
        #pragma unroll 8
        for (int kb = 0; kb < 32; ++kb) {
            bf16x8 b  = *(const bf16x8*)(bp + kb * 32);
            bf16x8 a0 = *(const bf16x8*)&hm[rr * 1032 + kb * 32 + q * 8];
            bf16x8 a1 = *(const bf16x8*)&hm[(16 + rr) * 1032 + kb * 32 + q * 8];
            c0 = __builtin_amdgcn_mfma_f32_16x16x32_bf16(a0, b, c0, 0, 0, 0);
            c1 = __builtin_amdgcn_mfma_f32_16x16x32_bf16(a1, b, c1, 0, 0, 0);
        }
        __builtin_amdgcn_s_setprio(0);
        acc2[0][ct] = c0; acc2[1][ct] = c1;
    }

    // ---- LN2 partial stats ----
    #pragma unroll
    for (int rt = 0; rt < 2; ++rt) {
        #pragma unroll
        for (int j = 0; j < 4; ++j) {
            float s = acc2[rt][0][j] + acc2[rt][1][j];
            float z = acc2[rt][0][j] * acc2[rt][0][j] + acc2[rt][1][j] * acc2[rt][1][j];
            s += __shfl_xor(s, 1); s += __shfl_xor(s, 2);
            s += __shfl_xor(s, 4); s += __shfl_xor(s, 8);
            z += __shfl_xor(z, 1); z += __shfl_xor(z, 2);
            z += __shfl_xor(z, 4); z += __shfl_xor(z, 8);
            if (rr == 0) {
                pst[rt * 16 + 4 * q + j][w][0] = s;
                pst[rt * 16 + 4 * q + j][w][1] = z;
            }
        }
    }
    __syncthreads();

    // ---- LN2 finalize + residual + relu -> bf16 out ----
    #pragma unroll
    for (int rt = 0; rt < 2; ++rt) {
        float mean2[4], rstd2[4];
        #pragma unroll
        for (int j = 0; j < 4; ++j) {
            const int row = rt * 16 + 4 * q + j;
            float s = 0.f, z = 0.f;
            #pragma unroll
            for (int k = 0; k < 8; ++k) { s += pst[row][k][0]; z += pst[row][k][1]; }
            float mean = s * (1.f / 256.f);
            float var = fmaxf(z * (1.f / 256.f) - mean * mean, 0.f);
            mean2[j] = mean;
            rstd2[j] = 1.0f / sqrtf(var + 1e-5f);
        }
        #pragma unroll
        for (int ct = 0; ct < 2; ++ct) {
            const int c = w * 32 + ct * 16 + rr;
            const float gg = g2[c], bb = b2[c];
            #pragma unroll
            for (int j = 0; j < 4; ++j) {
                const size_t row = R0 + rt * 16 + 4 * q + j;
                float v = (acc2[rt][ct][j] - mean2[j]) * rstd2[j] * gg + bb;
                float xv = 0.f;
                if (!guardRes || row < (size_t)N_PTS) xv = bf2f(xresb[row * 256 + c]);
                float o = v + xv;
                outb[row * 256 + c] = f2bf(o > 0.f ? o : 0.f);
            }
        }
    }
}

// ---------- final projection: bf16 input, B staged in LDS halves
__global__ __launch_bounds__(512, 4) void k_proj(
    const u16*   __restrict__ xinb,  // [NPAD][256] bf16
    const u16*   __restrict__ pjtp,  // [256][264]
    const float* __restrict__ pb,
    float*       __restrict__ out)
{
    __shared__ u16 Bs[128 * 264];
    const int tid = threadIdx.x, w = tid >> 6, lane = tid & 63;
    const int rr = lane & 15, q = lane >> 4;
    const size_t R0 = (size_t)blockIdx.x * 128 + (size_t)w * 16;

    int arn = (int)R0 + rr; if (arn >= N_PTS) arn = N_PTS - 1;
    const u16* arow = xinb + (size_t)arn * 256;
    bf16x8 afr[8];
    #pragma unroll
    for (int kb = 0; kb < 8; ++kb)
        afr[kb] = *(const bf16x8*)(arow + kb * 32 + q * 8);

    #pragma unroll 1
    for (int h = 0; h < 2; ++h) {
        if (h) __syncthreads();
        for (int o = tid * 16; o < 67584; o += 8192)
            *(uint4*)((char*)Bs + o) = *(const uint4*)((const char*)(pjtp + h * 128 * 264) + o);
        __syncthreads();
        #pragma unroll 2
        for (int nt8 = 0; nt8 < 8; ++nt8) {
            f32x4 acc = {0.f, 0.f, 0.f, 0.f};
            __builtin_amdgcn_s_setprio(1);
            #pragma unroll
            for (int kb = 0; kb < 8; ++kb) {
                bf16x8 b = *(const bf16x8*)&Bs[(nt8 * 16 + rr) * 264 + kb * 32 + q * 8];
                acc = __builtin_amdgcn_mfma_f32_16x16x32_bf16(afr[kb], b, acc, 0, 0, 0);
            }
            __builtin_amdgcn_s_setprio(0);
            const int c = h * 128 + nt8 * 16 + rr;
            const float bias = pb[c];
            #pragma unroll
            for (int j = 0; j < 4; ++j) {
                const size_t row = R0 + 4 * q + j;
                if (row < (size_t)N_PTS) out[row * 256 + c] = acc[j] + bias;
            }
        }
    }
}

extern "C" void kernel_launch(void* const* d_in, const int* in_sizes, int n_in,
                              void* d_out, int out_size, void* d_ws, size_t ws_size,
                              hipStream_t stream) {
    const float* p      = (const float*)d_in[0];
    const float* x      = (const float*)d_in[1];
    const float* nn     = (const float*)d_in[2];
    const int*   idx    = (const int*)d_in[3];
    const float* r      = (const float*)d_in[4];
    const float* emb_w1 = (const float*)d_in[5];
    const float* emb_g1 = (const float*)d_in[6];
    const float* emb_b1 = (const float*)d_in[7];
    const float* emb_w2 = (const float*)d_in[8];
    const float* conv_w = (const float*)d_in[9];
    const float* pw_w1  = (const float*)d_in[10];
    const float* pw_g1  = (const float*)d_in[11];
    const float* pw_b1  = (const float*)d_in[12];
    const float* pw_w2  = (const float*)d_in[13];
    const float* pw_g2  = (const float*)d_in[14];
    const float* pw_b2  = (const float*)d_in[15];
    const float* proj_w = (const float*)d_in[16];
    const float* proj_b = (const float*)d_in[17];
    float* out = (float*)d_out;

    char* ws = (char*)d_ws;
    const size_t SZB = (size_t)NPAD * 256 * sizeof(u16);   // 51.2 MB
    u16* xb0 = (u16*)ws;                   // bf16(x) / L1 pooled
    u16* PB  = (u16*)(ws + SZB);           // L0 pooled / L1 output
    u16* h1B = (u16*)(ws + 2 * SZB);       // L0 output (gather src + residual for L1)
    u16* f5b = (u16*)(ws + 3 * SZB);       // [N][16][5] bf16, 16 MB
    u16* wb  = f5b + (size_t)N_PTS * 16 * 5;
    u16* ew2tp  = wb;                      // [2][256][264]
    u16* pjtp   = ew2tp + 2 * 256 * 264;   // [256][264]
    u16* w1pad  = pjtp + 256 * 264;        // [2][256][32]
    u16* convbf = w1pad + 2 * 256 * 32;    // [2][64][64]
    u16* b1t    = convbf + 2 * 64 * 64;    // [2][1024][256]
    u16* b2t    = b1t + 2 * 1024 * 256;    // [2][256][1024]

    k_transpose_pad<<<(2*256*264 + 255)/256, 256, 0, stream>>>(emb_w2, ew2tp, 2, 256, 256, 264);
    k_transpose_pad<<<(256*264 + 255)/256, 256, 0, stream>>>(proj_w, pjtp, 1, 256, 256, 264);
    k_transpose_pad<<<(2*256*32 + 255)/256, 256, 0, stream>>>(emb_w1, w1pad, 2, 5, 256, 32);
    k_transpose_pad<<<(2*1024*256 + 255)/256, 256, 0, stream>>>(pw_w1, b1t, 2, 256, 1024, 256);
    k_transpose_pad<<<(2*256*1024 + 255)/256, 256, 0, stream>>>(pw_w2, b2t, 2, 1024, 256, 1024);
    k_cast_bf16<<<(2*64*64 + 255)/256, 256, 0, stream>>>(conv_w, convbf, 2*64*64);

    k_castx8<<<(N_PTS*256/8 + 255)/256, 256, 0, stream>>>(x, xb0, N_PTS*256/8);
    k_ppf<<<(N_PTS * 16 + 255)/256, 256, 0, stream>>>(p, nn, idx, r, f5b);

    // layer 0
    k_neighbor<<<N_PTS/16, 512, 0, stream>>>(xb0, f5b, idx, w1pad, emb_g1, emb_b1,
                                             ew2tp, convbf, PB);
    k_pointwise<<<NPAD/32, 512, 0, stream>>>(PB, xb0, h1B, b1t, pw_g1, pw_b1,
                                             b2t, pw_g2, pw_b2, 1);
    // layer 1
    k_neighbor<<<N_PTS/16, 512, 0, stream>>>(h1B, f5b, idx, w1pad + 256*32,
                                             emb_g1 + 256, emb_b1 + 256,
                                             ew2tp + 256*264, convbf + 64*64, xb0);
    k_pointwise<<<NPAD/32, 512, 0, stream>>>(xb0, h1B, PB, b1t + 1024*256,
                                             pw_g1 + 1024, pw_b1 + 1024,
                                             b2t + 256*1024, pw_g2 + 256, pw_b2 + 256, 0);
    // projection
    k_proj<<<(NPAD + 127)/128, 512, 0, stream>>>(PB, pjtp, proj_b, out);
}

// Round 14
// 2108.269 us; speedup vs baseline: 1.2032x; 1.0071x over previous
//
#include <hip/hip_runtime.h>
#include <hip/hip_bf16.h>
#include <stdint.h>

#define N_PTS 100000
#define NPAD  100032   // 64-divisible

typedef unsigned short u16;
typedef unsigned int   u32;
using bf16x8 = __attribute__((ext_vector_type(8))) short;
using f32x4  = __attribute__((ext_vector_type(4))) float;

__device__ __forceinline__ u16 f2bf(float f) {
    __hip_bfloat16 h = __float2bfloat16(f);
    return *reinterpret_cast<u16*>(&h);
}
__device__ __forceinline__ float bf2f(u16 h) {
    return __uint_as_float(((u32)h) << 16);
}

// ---------- padded transpose to bf16: dst[l][co][stride] = src[l][ci][co] (ci<R else 0)
__global__ __launch_bounds__(256) void k_transpose_pad(
    const float* __restrict__ src, u16* __restrict__ dst,
    int Lc, int R, int Cc, int stride) {
    int t = blockIdx.x * 256 + threadIdx.x;
    int total = Lc * Cc * stride;
    if (t >= total) return;
    int l = t / (Cc * stride);
    int rem = t - l * (Cc * stride);
    int co = rem / stride;
    int ci = rem - co * stride;
    dst[t] = (ci < R) ? f2bf(src[((size_t)l * R + ci) * Cc + co]) : (u16)0;
}

__global__ __launch_bounds__(256) void k_cast_bf16(
    const float* __restrict__ src, u16* __restrict__ dst, int total) {
    int t = blockIdx.x * 256 + threadIdx.x;
    if (t < total) dst[t] = f2bf(src[t]);
}

// vectorized fp32 -> bf16 cast, 8 elements/thread
__global__ __launch_bounds__(256) void k_castx8(
    const float* __restrict__ src, u16* __restrict__ dst, int total8) {
    int t = blockIdx.x * 256 + threadIdx.x;
    if (t >= total8) return;
    float4 a = *(const float4*)(src + (size_t)t * 8);
    float4 b = *(const float4*)(src + (size_t)t * 8 + 4);
    uint4 o;
    o.x = (u32)f2bf(a.x) | ((u32)f2bf(a.y) << 16);
    o.y = (u32)f2bf(a.z) | ((u32)f2bf(a.w) << 16);
    o.z = (u32)f2bf(b.x) | ((u32)f2bf(b.y) << 16);
    o.w = (u32)f2bf(b.z) | ((u32)f2bf(b.w) << 16);
    *(uint4*)(dst + (size_t)t * 8) = o;
}

// ---------- PPF features (bf16 output)
__device__ __forceinline__ float angf(float ax, float ay, float az,
                                      float bx, float by, float bz) {
    float cx = ay * bz - az * by;
    float cy = az * bx - ax * bz;
    float cz = ax * by - ay * bx;
    float cr = sqrtf(cx * cx + cy * cy + cz * cz);
    float dt = ax * bx + ay * by + az * bz;
    return atan2f(cr, dt);
}

__global__ __launch_bounds__(256) void k_ppf(
    const float* __restrict__ p, const float* __restrict__ nrm,
    const int* __restrict__ idx, const float* __restrict__ r,
    u16* __restrict__ f5b) {
    int t = blockIdx.x * 256 + threadIdx.x;
    if (t >= N_PTS * 16) return;
    int i = t >> 4;
    int j = idx[(size_t)i * 32 + (t & 15)];
    float pix = p[(size_t)i*3], piy = p[(size_t)i*3+1], piz = p[(size_t)i*3+2];
    float pjx = p[(size_t)j*3], pjy = p[(size_t)j*3+1], pjz = p[(size_t)j*3+2];
    float dx = pjx - pix, dy = pjy - piy, dz = pjz - piz;
    float dist = sqrtf(dx*dx + dy*dy + dz*dz);
    float nix = nrm[(size_t)i*3], niy = nrm[(size_t)i*3+1], niz = nrm[(size_t)i*3+2];
    float njx = nrm[(size_t)j*3], njy = nrm[(size_t)j*3+1], njz = nrm[(size_t)j*3+2];
    float a1 = angf(nix, niy, niz, dx, dy, dz);
    float a2 = angf(njx, njy, njz, dx, dy, dz);
    float a3 = angf(nix, niy, niz, njx, njy, njz);
    float rinv = 1.0f / r[0];
    u16* o = f5b + (size_t)t * 5;
    o[0] = f2bf(a1); o[1] = f2bf(a2); o[2] = f2bf(a3);
    o[3] = f2bf(dist); o[4] = f2bf(dist * rinv);
}

// Build an h A-fragment (m = neighbor rr, k = couts) from swapped-emb D-tiles.
__device__ __forceinline__ bf16x8 fixup_frag(const uint2* pk, int kt,
                                             int srcA, int srcB, bool hiT) {
    int aLx = __shfl((int)pk[2*kt].x,   srcA);
    int aHx = __shfl((int)pk[2*kt+1].x, srcA);
    int aLy = __shfl((int)pk[2*kt].y,   srcA);
    int aHy = __shfl((int)pk[2*kt+1].y, srcA);
    int bLx = __shfl((int)pk[2*kt].x,   srcB);
    int bHx = __shfl((int)pk[2*kt+1].x, srcB);
    int bLy = __shfl((int)pk[2*kt].y,   srcB);
    int bHy = __shfl((int)pk[2*kt+1].y, srcB);
    uint4 u;
    u.x = (u32)(hiT ? aHx : aLx);
    u.y = (u32)(hiT ? aHy : aLy);
    u.z = (u32)(hiT ? bHx : bLx);
    u.w = (u32)(hiT ? bHy : bLy);
    return *(bf16x8*)&u;
}

// ---------- neighbor stage (R13 verbatim): 16 pts/block, 512 thr, 2 blocks/CU.
__global__ __launch_bounds__(512, 4) void k_neighbor(
    const u16*   __restrict__ xcur,
    const u16*   __restrict__ f5b,
    const int*   __restrict__ idx,
    const u16*   __restrict__ w1pad,
    const float* __restrict__ g1, const float* __restrict__ b1,
    const u16*   __restrict__ ew2tp,
    const u16*   __restrict__ convbf,
    u16*         __restrict__ pooledb)
{
    __shared__ u16 Bs[64 * 264];
    __shared__ u16 posw[8][2][16][72];
    __shared__ u16 pbounce[8][2][256];
    __shared__ int idxs[16][16];

    const int tid = threadIdx.x, w = tid >> 6, lane = tid & 63;
    const int rr = lane & 15, q = lane >> 4;
    const int i0 = blockIdx.x * 16;

    for (int o = tid * 16; o < 33792; o += 8192)
        *(uint4*)((char*)Bs + o) = *(const uint4*)((const char*)ew2tp + o);
    if (tid < 256)
        idxs[tid >> 4][tid & 15] = idx[(size_t)(i0 + (tid >> 4)) * 32 + (tid & 15)];

    const int srcA = rr + ((q & 1) << 5);
    const int srcB = srcA + 16;
    const bool hiT = (q >> 1) != 0;

    bf16x8 hfrag[2][8];
    #pragma unroll
    for (int rt = 0; rt < 2; ++rt) {
        const int pt = i0 + 2 * w + rt;
        bf16x8 a1;
        #pragma unroll
        for (int e = 0; e < 8; ++e) a1[e] = 0;
        if (q == 0) {
            const u16* fp = f5b + (size_t)(pt * 16 + rr) * 5;
            a1[0] = (short)fp[0]; a1[1] = (short)fp[1];
            a1[2] = (short)fp[2]; a1[3] = (short)fp[3];
            a1[4] = (short)fp[4];
        }
        f32x4 hacc[16];
        __builtin_amdgcn_s_setprio(1);
        #pragma unroll
        for (int ct = 0; ct < 16; ++ct) {
            bf16x8 aW = *(const bf16x8*)&w1pad[(ct * 16 + rr) * 32 + q * 8];
            f32x4 z = {0.f, 0.f, 0.f, 0.f};
            hacc[ct] = __builtin_amdgcn_mfma_f32_16x16x32_bf16(aW, a1, z, 0, 0, 0);
        }
        __builtin_amdgcn_s_setprio(0);
        float s = 0.f, z2 = 0.f;
        #pragma unroll
        for (int ct = 0; ct < 16; ++ct) {
            #pragma unroll
            for (int j = 0; j < 4; ++j) { float v = hacc[ct][j]; s += v; z2 += v * v; }
        }
        s  += __shfl_xor(s, 16);  s  += __shfl_xor(s, 32);
        z2 += __shfl_xor(z2, 16); z2 += __shfl_xor(z2, 32);
        float mean = s * (1.f / 256.f);
        float var = fmaxf(z2 * (1.f / 256.f) - mean * mean, 0.f);
        float rstd = 1.0f / sqrtf(var + 1e-5f);

        uint2 pk[16];
        #pragma unroll
        for (int ct = 0; ct < 16; ++ct) {
            const int c0 = ct * 16 + 4 * q;
            float4 gg = *(const float4*)&g1[c0];
            float4 bb = *(const float4*)&b1[c0];
            float v0 = (hacc[ct][0] - mean) * rstd * gg.x + bb.x;
            float v1 = (hacc[ct][1] - mean) * rstd * gg.y + bb.y;
            float v2 = (hacc[ct][2] - mean) * rstd * gg.z + bb.z;
            float v3 = (hacc[ct][3] - mean) * rstd * gg.w + bb.w;
            v0 = v0 > 0.f ? v0 : 0.1f * v0;
            v1 = v1 > 0.f ? v1 : 0.1f * v1;
            v2 = v2 > 0.f ? v2 : 0.1f * v2;
            v3 = v3 > 0.f ? v3 : 0.1f * v3;
            pk[ct].x = (u32)f2bf(v0) | ((u32)f2bf(v1) << 16);
            pk[ct].y = (u32)f2bf(v2) | ((u32)f2bf(v3) << 16);
        }
        #pragma unroll
        for (int kt = 0; kt < 8; ++kt)
            hfrag[rt][kt] = fixup_frag(pk, kt, srcA, srcB, hiT);
    }
    __syncthreads();

    const int ppt = lane >> 5, cl = lane & 31;
    const int* ixp = idxs[2 * w + ppt];

    #pragma unroll 1
    for (int p = 0; p < 4; ++p) {
        __builtin_amdgcn_s_setprio(1);
        #pragma unroll
        for (int nt4 = 0; nt4 < 4; ++nt4) {
            f32x4 a0 = {0.f,0.f,0.f,0.f}, a1v = {0.f,0.f,0.f,0.f};
            #pragma unroll
            for (int kb = 0; kb < 8; ++kb) {
                bf16x8 bb = *(const bf16x8*)&Bs[(nt4 * 16 + rr) * 264 + kb * 32 + q * 8];
                a0  = __builtin_amdgcn_mfma_f32_16x16x32_bf16(hfrag[0][kb], bb, a0, 0, 0, 0);
                a1v = __builtin_amdgcn_mfma_f32_16x16x32_bf16(hfrag[1][kb], bb, a1v, 0, 0, 0);
            }
            #pragma unroll
            for (int j = 0; j < 4; ++j) {
                posw[w][0][4 * q + j][nt4 * 16 + rr] = f2bf(a0[j]);
                posw[w][1][4 * q + j][nt4 * 16 + rr] = f2bf(a1v[j]);
            }
        }
        __builtin_amdgcn_s_setprio(0);
        if (p < 3) {
            __syncthreads();
            const char* src = (const char*)(ew2tp + (size_t)(p + 1) * 64 * 264);
            for (int o = tid * 16; o < 33792; o += 8192)
                *(uint4*)((char*)Bs + o) = *(const uint4*)(src + o);
        }
        if (p == 0) {
            #pragma unroll
            for (int pt = 0; pt < 2; ++pt) {
                const u16* xr = xcur + (size_t)idxs[2 * w + pt][rr] * 256;
                bf16x8 gA[2];
                #pragma unroll
                for (int kb = 0; kb < 2; ++kb) {
                    bf16x8 xa = *(const bf16x8*)(xr + kb * 32 + q * 8);
                    bf16x8 pv = *(const bf16x8*)&posw[w][pt][rr][kb * 32 + q * 8];
                    bf16x8 g;
                    #pragma unroll
                    for (int e = 0; e < 8; ++e)
                        g[e] = (short)f2bf(bf2f((u16)xa[e]) + bf2f((u16)pv[e]));
                    gA[kb] = g;
                }
                __builtin_amdgcn_s_setprio(1);
                #pragma unroll
                for (int cn = 0; cn < 4; ++cn) {
                    bf16x8 cB0 = *(const bf16x8*)&convbf[(cn * 16 + rr) * 64 + q * 8];
                    bf16x8 cB1 = *(const bf16x8*)&convbf[(cn * 16 + rr) * 64 + 32 + q * 8];
                    f32x4 z = {0.f,0.f,0.f,0.f};
                    f32x4 acc = __builtin_amdgcn_mfma_f32_16x16x32_bf16(gA[0], cB0, z, 0, 0, 0);
                    acc = __builtin_amdgcn_mfma_f32_16x16x32_bf16(gA[1], cB1, acc, 0, 0, 0);
                    float m = fmaxf(fmaxf(acc[0], acc[1]), fmaxf(acc[2], acc[3]));
                    m = fmaxf(m, __shfl_xor(m, 16));
                    m = fmaxf(m, __shfl_xor(m, 32));
                    if (lane < 16) pbounce[w][pt][cn * 16 + lane] = f2bf(m);
                }
                __builtin_amdgcn_s_setprio(0);
            }
        } else {
            const int cq = p * 64 + cl * 2;
            u32 xv[16];
            #pragma unroll
            for (int k = 0; k < 16; ++k)
                xv[k] = *(const u32*)(xcur + (size_t)ixp[k] * 256 + cq);
            float m0 = -3e38f, m1 = -3e38f;
            #pragma unroll
            for (int k = 0; k < 16; ++k) {
                u32 pv = *(const u32*)&posw[w][ppt][k][cl * 2];
                float gv0 = bf2f((u16)(pv & 0xffffu)) + bf2f((u16)(xv[k] & 0xffffu));
                float gv1 = bf2f((u16)(pv >> 16))     + bf2f((u16)(xv[k] >> 16));
                m0 = fmaxf(m0, gv0);
                m1 = fmaxf(m1, gv1);
            }
            *(u32*)&pbounce[w][ppt][cq] = (u32)f2bf(m0) | ((u32)f2bf(m1) << 16);
        }
        if (p < 3) __syncthreads();
    }
    {
        const int pt = lane >> 5, off = (lane & 31) * 8;
        uint4 v = *(const uint4*)&pbounce[w][pt][off];
        *(uint4*)(pooledb + (size_t)(i0 + 2 * w + pt) * 256 + off) = v;
    }
}

// ---------- pointwise v8: bf16 I/O + setprio; optional FUSED final projection.
// doProj=0: write outb (bf16). doProj=1: h2 -> LDS -> GEMM3 (pjtp from L2) -> outf fp32.
__global__ __launch_bounds__(512, 4) void k_pointwise(
    const u16* poolb,
    const u16* __restrict__ xresb,
    u16*       outb,
    const u16* __restrict__ b1t,
    const float* __restrict__ g1, const float* __restrict__ b1,
    const u16* __restrict__ b2t,
    const float* __restrict__ g2, const float* __restrict__ b2,
    int guardRes,
    const u16* __restrict__ pjtp,   // [256][264] proj_w^T (used when doProj)
    const float* __restrict__ pb,   // [256] proj_b
    float* __restrict__ outf,       // [N][256] fp32 final output
    int doProj)
{
    __shared__ u16 hm[32 * 1032];      // 66,048 B (reused as 32x264 h2 tile for GEMM3)
    __shared__ float pst[32][8][2];

    const int tid = threadIdx.x, w = tid >> 6, lane = tid & 63;
    const int rr = lane & 15, q = lane >> 4;
    const size_t R0 = (size_t)blockIdx.x * 32;

    bf16x8 afr[2][8];
    #pragma unroll
    for (int rt = 0; rt < 2; ++rt) {
        int ar = (int)R0 + rt * 16 + rr; if (ar >= N_PTS) ar = N_PTS - 1;
        const u16* arow = poolb + (size_t)ar * 256;
        #pragma unroll
        for (int kb = 0; kb < 8; ++kb)
            afr[rt][kb] = *(const bf16x8*)(arow + kb * 32 + q * 8);
    }

    // ---- GEMM1 ----
    #pragma unroll 2
    for (int ct = 0; ct < 8; ++ct) {
        const int co = w * 128 + ct * 16 + rr;
        const u16* bp = b1t + (size_t)co * 256 + q * 8;
        bf16x8 bb[8];
        #pragma unroll
        for (int kb = 0; kb < 8; ++kb) bb[kb] = *(const bf16x8*)(bp + kb * 32);
        f32x4 a0 = {0.f,0.f,0.f,0.f}, a1v = {0.f,0.f,0.f,0.f};
        __builtin_amdgcn_s_setprio(1);
        #pragma unroll
        for (int kb = 0; kb < 8; ++kb) {
            a0  = __builtin_amdgcn_mfma_f32_16x16x32_bf16(afr[0][kb], bb[kb], a0, 0, 0, 0);
            a1v = __builtin_amdgcn_mfma_f32_16x16x32_bf16(afr[1][kb], bb[kb], a1v, 0, 0, 0);
        }
        __builtin_amdgcn_s_setprio(0);
        #pragma unroll
        for (int j = 0; j < 4; ++j) {
            hm[(4 * q + j) * 1032 + co]      = f2bf(a0[j]);
            hm[(16 + 4 * q + j) * 1032 + co] = f2bf(a1v[j]);
        }
    }
    __syncthreads();

    // ---- LN1 + leaky ----
    {
        const int row = tid >> 4;
        const int t16 = tid & 15;
        u32* hm32 = (u32*)hm;
        const int base = row * 516;
        float s = 0.f, z = 0.f;
        #pragma unroll 8
        for (int e = 0; e < 32; ++e) {
            u32 pk = hm32[base + t16 + 16 * e];
            float v0 = bf2f((u16)(pk & 0xffffu)), v1 = bf2f((u16)(pk >> 16));
            s += v0 + v1; z += v0 * v0 + v1 * v1;
        }
        s += __shfl_xor(s, 1); s += __shfl_xor(s, 2);
        s += __shfl_xor(s, 4); s += __shfl_xor(s, 8);
        z += __shfl_xor(z, 1); z += __shfl_xor(z, 2);
        z += __shfl_xor(z, 4); z += __shfl_xor(z, 8);
        float mean = s * (1.f / 1024.f);
        float var = fmaxf(z * (1.f / 1024.f) - mean * mean, 0.f);
        float rstd = 1.0f / sqrtf(var + 1e-5f);
        #pragma unroll 4
        for (int e = 0; e < 32; ++e) {
            const int cidx = t16 + 16 * e;
            u32 pk = hm32[base + cidx];
            const int c = cidx * 2;
            float2 gg = *(const float2*)&g1[c];
            float2 bbv = *(const float2*)&b1[c];
            float v0 = (bf2f((u16)(pk & 0xffffu)) - mean) * rstd * gg.x + bbv.x;
            float v1 = (bf2f((u16)(pk >> 16))     - mean) * rstd * gg.y + bbv.y;
            v0 = v0 > 0.f ? v0 : 0.1f * v0;
            v1 = v1 > 0.f ? v1 : 0.1f * v1;
            hm32[base + cidx] = (u32)f2bf(v0) | ((u32)f2bf(v1) << 16);
        }
    }
    __syncthreads();

    // ---- GEMM2 ----
    f32x4 acc2[2][2];
    #pragma unroll
    for (int ct = 0; ct < 2; ++ct) {
        const int cB = w * 32 + ct * 16 + rr;
        const u16* bp = b2t + (size_t)cB * 1024 + q * 8;
        f32x4 c0 = {0.f,0.f,0.f,0.f}, c1 = {0.f,0.f,0.f,0.f};
        __builtin_amdgcn_s_setprio(1);
        #pragma unroll 8
        for (int kb = 0; kb < 32; ++kb) {
            bf16x8 b  = *(const bf16x8*)(bp + kb * 32);
            bf16x8 a0 = *(const bf16x8*)&hm[rr * 1032 + kb * 32 + q * 8];
            bf16x8 a1 = *(const bf16x8*)&hm[(16 + rr) * 1032 + kb * 32 + q * 8];
            c0 = __builtin_amdgcn_mfma_f32_16x16x32_bf16(a0, b, c0, 0, 0, 0);
            c1 = __builtin_amdgcn_mfma_f32_16x16x32_bf16(a1, b, c1, 0, 0, 0);
        }
        __builtin_amdgcn_s_setprio(0);
        acc2[0][ct] = c0; acc2[1][ct] = c1;
    }

    // ---- LN2 partial stats ----
    #pragma unroll
    for (int rt = 0; rt < 2; ++rt) {
        #pragma unroll
        for (int j = 0; j < 4; ++j) {
            float s = acc2[rt][0][j] + acc2[rt][1][j];
            float z = acc2[rt][0][j] * acc2[rt][0][j] + acc2[rt][1][j] * acc2[rt][1][j];
            s += __shfl_xor(s, 1); s += __shfl_xor(s, 2);
            s += __shfl_xor(s, 4); s += __shfl_xor(s, 8);
            z += __shfl_xor(z, 1); z += __shfl_xor(z, 2);
            z += __shfl_xor(z, 4); z += __shfl_xor(z, 8);
            if (rr == 0) {
                pst[rt * 16 + 4 * q + j][w][0] = s;
                pst[rt * 16 + 4 * q + j][w][1] = z;
            }
        }
    }
    __syncthreads();   // also: all GEMM2 hm reads complete -> hm reusable

    // ---- LN2 finalize + residual + relu ----
    #pragma unroll
    for (int rt = 0; rt < 2; ++rt) {
        float mean2[4], rstd2[4];
        #pragma unroll
        for (int j = 0; j < 4; ++j) {
            const int row = rt * 16 + 4 * q + j;
            float s = 0.f, z = 0.f;
            #pragma unroll
            for (int k = 0; k < 8; ++k) { s += pst[row][k][0]; z += pst[row][k][1]; }
            float mean = s * (1.f / 256.f);
            float var = fmaxf(z * (1.f / 256.f) - mean * mean, 0.f);
            mean2[j] = mean;
            rstd2[j] = 1.0f / sqrtf(var + 1e-5f);
        }
        #pragma unroll
        for (int ct = 0; ct < 2; ++ct) {
            const int c = w * 32 + ct * 16 + rr;
            const float gg = g2[c], bb = b2[c];
            #pragma unroll
            for (int j = 0; j < 4; ++j) {
                const size_t row = R0 + rt * 16 + 4 * q + j;
                float v = (acc2[rt][ct][j] - mean2[j]) * rstd2[j] * gg + bb;
                float xv = 0.f;
                if (!guardRes || row < (size_t)N_PTS) xv = bf2f(xresb[row * 256 + c]);
                float o = v + xv;
                u16 hb = f2bf(o > 0.f ? o : 0.f);
                if (doProj) {
                    // stash h2 tile in reused hm (stride 264), per-wave disjoint cols
                    hm[(rt * 16 + 4 * q + j) * 264 + c] = hb;
                } else {
                    outb[row * 256 + c] = hb;
                }
            }
        }
    }
    if (!doProj) return;

    // ---- fused projection: out = h2 @ proj_w + proj_b (K=256, B from L2) ----
    __syncthreads();   // h2 tile complete in hm
    bf16x8 a3[2][8];
    #pragma unroll
    for (int rt = 0; rt < 2; ++rt)
        #pragma unroll
        for (int kb = 0; kb < 8; ++kb)
            a3[rt][kb] = *(const bf16x8*)&hm[(rt * 16 + rr) * 264 + kb * 32 + q * 8];
    #pragma unroll
    for (int ct = 0; ct < 2; ++ct) {
        const int cout = w * 32 + ct * 16 + rr;
        const u16* bp = pjtp + (size_t)cout * 264 + q * 8;
        bf16x8 bb[8];
        #pragma unroll
        for (int kb = 0; kb < 8; ++kb) bb[kb] = *(const bf16x8*)(bp + kb * 32);
        f32x4 c0 = {0.f,0.f,0.f,0.f}, c1 = {0.f,0.f,0.f,0.f};
        __builtin_amdgcn_s_setprio(1);
        #pragma unroll
        for (int kb = 0; kb < 8; ++kb) {
            c0 = __builtin_amdgcn_mfma_f32_16x16x32_bf16(a3[0][kb], bb[kb], c0, 0, 0, 0);
            c1 = __builtin_amdgcn_mfma_f32_16x16x32_bf16(a3[1][kb], bb[kb], c1, 0, 0, 0);
        }
        __builtin_amdgcn_s_setprio(0);
        const float bias = pb[cout];
        #pragma unroll
        for (int rt = 0; rt < 2; ++rt) {
            const f32x4 acc = rt ? c1 : c0;
            #pragma unroll
            for (int j = 0; j < 4; ++j) {
                const size_t row = R0 + rt * 16 + 4 * q + j;
                if (row < (size_t)N_PTS) outf[row * 256 + cout] = acc[j] + bias;
            }
        }
    }
}

extern "C" void kernel_launch(void* const* d_in, const int* in_sizes, int n_in,
                              void* d_out, int out_size, void* d_ws, size_t ws_size,
                              hipStream_t stream) {
    const float* p      = (const float*)d_in[0];
    const float* x      = (const float*)d_in[1];
    const float* nn     = (const float*)d_in[2];
    const int*   idx    = (const int*)d_in[3];
    const float* r      = (const float*)d_in[4];
    const float* emb_w1 = (const float*)d_in[5];
    const float* emb_g1 = (const float*)d_in[6];
    const float* emb_b1 = (const float*)d_in[7];
    const float* emb_w2 = (const float*)d_in[8];
    const float* conv_w = (const float*)d_in[9];
    const float* pw_w1  = (const float*)d_in[10];
    const float* pw_g1  = (const float*)d_in[11];
    const float* pw_b1  = (const float*)d_in[12];
    const float* pw_w2  = (const float*)d_in[13];
    const float* pw_g2  = (const float*)d_in[14];
    const float* pw_b2  = (const float*)d_in[15];
    const float* proj_w = (const float*)d_in[16];
    const float* proj_b = (const float*)d_in[17];
    float* out = (float*)d_out;

    char* ws = (char*)d_ws;
    const size_t SZB = (size_t)NPAD * 256 * sizeof(u16);   // 51.2 MB
    u16* xb0 = (u16*)ws;                   // bf16(x) / L1 pooled
    u16* PB  = (u16*)(ws + SZB);           // L0 pooled
    u16* h1B = (u16*)(ws + 2 * SZB);       // L0 output (gather src + residual for L1)
    u16* f5b = (u16*)(ws + 3 * SZB);       // [N][16][5] bf16, 16 MB
    u16* wb  = f5b + (size_t)N_PTS * 16 * 5;
    u16* ew2tp  = wb;                      // [2][256][264]
    u16* pjtp   = ew2tp + 2 * 256 * 264;   // [256][264]
    u16* w1pad  = pjtp + 256 * 264;        // [2][256][32]
    u16* convbf = w1pad + 2 * 256 * 32;    // [2][64][64]
    u16* b1t    = convbf + 2 * 64 * 64;    // [2][1024][256]
    u16* b2t    = b1t + 2 * 1024 * 256;    // [2][256][1024]

    k_transpose_pad<<<(2*256*264 + 255)/256, 256, 0, stream>>>(emb_w2, ew2tp, 2, 256, 256, 264);
    k_transpose_pad<<<(256*264 + 255)/256, 256, 0, stream>>>(proj_w, pjtp, 1, 256, 256, 264);
    k_transpose_pad<<<(2*256*32 + 255)/256, 256, 0, stream>>>(emb_w1, w1pad, 2, 5, 256, 32);
    k_transpose_pad<<<(2*1024*256 + 255)/256, 256, 0, stream>>>(pw_w1, b1t, 2, 256, 1024, 256);
    k_transpose_pad<<<(2*256*1024 + 255)/256, 256, 0, stream>>>(pw_w2, b2t, 2, 1024, 256, 1024);
    k_cast_bf16<<<(2*64*64 + 255)/256, 256, 0, stream>>>(conv_w, convbf, 2*64*64);

    k_castx8<<<(N_PTS*256/8 + 255)/256, 256, 0, stream>>>(x, xb0, N_PTS*256/8);
    k_ppf<<<(N_PTS * 16 + 255)/256, 256, 0, stream>>>(p, nn, idx, r, f5b);

    // layer 0
    k_neighbor<<<N_PTS/16, 512, 0, stream>>>(xb0, f5b, idx, w1pad, emb_g1, emb_b1,
                                             ew2tp, convbf, PB);
    k_pointwise<<<NPAD/32, 512, 0, stream>>>(PB, xb0, h1B, b1t, pw_g1, pw_b1,
                                             b2t, pw_g2, pw_b2, 1,
                                             pjtp, proj_b, out, 0);
    // layer 1 (+ fused projection)
    k_neighbor<<<N_PTS/16, 512, 0, stream>>>(h1B, f5b, idx, w1pad + 256*32,
                                             emb_g1 + 256, emb_b1 + 256,
                                             ew2tp + 256*264, convbf + 64*64, xb0);
    k_pointwise<<<NPAD/32, 512, 0, stream>>>(xb0, h1B, (u16*)PB, b1t + 1024*256,
                                             pw_g1 + 1024, pw_b1 + 1024,
                                             b2t + 256*1024, pw_g2 + 256, pw_b2 + 256, 0,
                                             pjtp, proj_b, out, 1);
}